// Round 1
// baseline (57.786 us; speedup 1.0000x reference)
//
#include <hip/hip_runtime.h>
#include <stdint.h>

#define NPRED 16384
#define NGT   128
#define KSEL  64
#define CAP   2048
#define THREADS 256

// Outputs (all float32, concatenated): ious[16*128*64], mask[16*128*64], k_idx[16*128*64]
#define OUT_IOUS 0
#define OUT_MASK (16 * NGT * KSEL)
#define OUT_KIDX (2 * 16 * NGT * KSEL)

__global__ __launch_bounds__(THREADS) void atss_kernel(
    const float* __restrict__ pred,  // [16][16384][4] cxcywh
    const float* __restrict__ gt,    // [16][128][4]  cxcywh
    float* __restrict__ out)
{
    __shared__ unsigned long long cand[CAP];
    __shared__ int s_cnt;
    __shared__ float ious_s[KSEL];
    __shared__ float r8[8];
    __shared__ float s_mean, s_thr;

    const int task = blockIdx.x;          // b*128 + g
    const int b    = task >> 7;
    const int tid  = threadIdx.x;
    const int lane = tid & 63;

    const float* gtp = gt + task * 4;
    const float gcx = gtp[0], gcy = gtp[1], gw = gtp[2], gh = gtp[3];
    const float* pb = pred + (size_t)b * NPRED * 4;

    // ---- Phase 1: threshold-filtered candidate collection (exact, with retry) ----
    unsigned int T = __float_as_uint(0.075f);
    int C = 0;
    for (int attempt = 0; attempt < 16; ++attempt) {
        if (tid == 0) s_cnt = 0;
        __syncthreads();
        for (int i = tid; i < NPRED; i += THREADS) {
            const float4 p = *reinterpret_cast<const float4*>(pb + i * 4);
            // numpy-exact f32 distance: sqrt((g-p.x)^2 + (g-p.y)^2), no FMA
            float dx = __fsub_rn(gcx, p.x);
            float dy = __fsub_rn(gcy, p.y);
            float d2 = __fadd_rn(__fmul_rn(dx, dx), __fmul_rn(dy, dy));
            float d  = __fsqrt_rn(d2);
            unsigned int bits = __float_as_uint(d);   // monotone for d >= 0
            bool c = bits < T;
            unsigned long long ball = __ballot(c);
            int n = __popcll(ball);
            int base = 0;
            if (lane == 0 && n) base = atomicAdd(&s_cnt, n);
            base = __shfl(base, 0, 64);
            if (c) {
                int pos = base + __popcll(ball & ((1ull << lane) - 1ull));
                if (pos < CAP)
                    cand[pos] = ((unsigned long long)bits << 32) | (unsigned int)i;
            }
        }
        __syncthreads();
        C = s_cnt;
        if (C >= KSEL && C <= CAP) break;
        if (C < KSEL) T += 0x00800000u;   // double radius (exp+1)
        else          T -= 0x00800000u;   // halve radius
        __syncthreads();
    }
    if (C > CAP) C = CAP;  // unreachable with this data; safety only

    // ---- Phase 2: bitonic sort of candidates by (dist_bits, idx) ascending ----
    int S = KSEL;
    while (S < C) S <<= 1;                // S <= CAP (pow2)
    for (int i = C + tid; i < S; i += THREADS) cand[i] = ~0ull;  // pad with +inf keys
    __syncthreads();
    for (int k = 2; k <= S; k <<= 1) {
        for (int j = k >> 1; j > 0; j >>= 1) {
            for (int i = tid; i < S; i += THREADS) {
                int p = i ^ j;
                if (p > i) {
                    unsigned long long a = cand[i], bb = cand[p];
                    bool up = ((i & k) == 0);
                    if ((a > bb) == up) { cand[i] = bb; cand[p] = a; }
                }
            }
            __syncthreads();
        }
    }

    // ---- Phase 3: epilogue — IoU, mean+std(ddof=1) threshold, mask (numpy-exact f32) ----
    const float gx1 = __fsub_rn(gcx, __fmul_rn(0.5f, gw));
    const float gy1 = __fsub_rn(gcy, __fmul_rn(0.5f, gh));
    const float gx2 = __fadd_rn(gcx, __fmul_rn(0.5f, gw));
    const float gy2 = __fadd_rn(gcy, __fmul_rn(0.5f, gh));

    float iou = 0.0f, kcx = 0.0f, kcy = 0.0f;
    int idx = 0;
    if (tid < KSEL) {
        unsigned long long key = cand[tid];
        idx = (int)(unsigned int)key;
        const float4 kb = *reinterpret_cast<const float4*>(pb + idx * 4);
        kcx = kb.x; kcy = kb.y;
        float kx1 = __fsub_rn(kb.x, __fmul_rn(0.5f, kb.z));
        float ky1 = __fsub_rn(kb.y, __fmul_rn(0.5f, kb.w));
        float kx2 = __fadd_rn(kb.x, __fmul_rn(0.5f, kb.z));
        float ky2 = __fadd_rn(kb.y, __fmul_rn(0.5f, kb.w));
        float ltx = fmaxf(gx1, kx1), lty = fmaxf(gy1, ky1);
        float rbx = fminf(gx2, kx2), rby = fminf(gy2, ky2);
        float wx = fmaxf(__fsub_rn(rbx, ltx), 0.0f);
        float wy = fmaxf(__fsub_rn(rby, lty), 0.0f);
        float inter = __fmul_rn(wx, wy);
        float ag = __fmul_rn(__fsub_rn(gx2, gx1), __fsub_rn(gy2, gy1));
        float ak = __fmul_rn(__fsub_rn(kx2, kx1), __fsub_rn(ky2, ky1));
        float uni = __fsub_rn(__fadd_rn(ag, ak), inter);
        iou = __fdiv_rn(inter, uni);
        ious_s[tid] = iou;
    }
    __syncthreads();

    // numpy pairwise sum (n=64): r[j] = a[j]+a[j+8]+...+a[j+56], then
    // ((r0+r1)+(r2+r3)) + ((r4+r5)+(r6+r7))
    if (tid < 8) {
        float r = ious_s[tid];
        #pragma unroll
        for (int i = 8; i < 64; i += 8) r = __fadd_rn(r, ious_s[tid + i]);
        r8[tid] = r;
    }
    __syncthreads();
    if (tid == 0) {
        float s = __fadd_rn(
            __fadd_rn(__fadd_rn(r8[0], r8[1]), __fadd_rn(r8[2], r8[3])),
            __fadd_rn(__fadd_rn(r8[4], r8[5]), __fadd_rn(r8[6], r8[7])));
        s_mean = __fdiv_rn(s, 64.0f);
    }
    __syncthreads();
    const float mean = s_mean;
    if (tid < KSEL) {
        float d = __fsub_rn(iou, mean);
        ious_s[tid] = __fmul_rn(d, d);
    }
    __syncthreads();
    if (tid < 8) {
        float r = ious_s[tid];
        #pragma unroll
        for (int i = 8; i < 64; i += 8) r = __fadd_rn(r, ious_s[tid + i]);
        r8[tid] = r;
    }
    __syncthreads();
    if (tid == 0) {
        float s = __fadd_rn(
            __fadd_rn(__fadd_rn(r8[0], r8[1]), __fadd_rn(r8[2], r8[3])),
            __fadd_rn(__fadd_rn(r8[4], r8[5]), __fadd_rn(r8[6], r8[7])));
        float var = __fdiv_rn(s, 63.0f);
        s_thr = __fadd_rn(mean, __fsqrt_rn(var));
    }
    __syncthreads();

    if (tid < KSEL) {
        bool inside = (gx1 <= kcx) && (kcx <= gx2) && (gy1 <= kcy) && (kcy <= gy2);
        bool m = (iou >= s_thr) && inside;
        int o = task * KSEL + tid;
        out[OUT_IOUS + o] = iou;
        out[OUT_MASK + o] = m ? 1.0f : 0.0f;
        out[OUT_KIDX + o] = (float)idx;
    }
}

extern "C" void kernel_launch(void* const* d_in, const int* in_sizes, int n_in,
                              void* d_out, int out_size, void* d_ws, size_t ws_size,
                              hipStream_t stream) {
    const float* pred = (const float*)d_in[0];  // (16,16384,4) f32
    const float* gtb  = (const float*)d_in[1];  // (16,128,4)   f32
    float* out = (float*)d_out;
    dim3 grid(16 * NGT);
    dim3 block(THREADS);
    hipLaunchKernelGGL(atss_kernel, grid, block, 0, stream, pred, gtb, out);
}

// Round 2
// 45.033 us; speedup vs baseline: 1.2832x; 1.2832x over previous
//
#include <hip/hip_runtime.h>
#include <stdint.h>

#define NPRED 16384
#define NGT   128
#define KSEL  64
#define CAP   2048
#define THREADS 256

// Outputs (all float32, concatenated): ious[16*128*64], mask[16*128*64], k_idx[16*128*64]
#define OUT_IOUS 0
#define OUT_MASK (16 * NGT * KSEL)
#define OUT_KIDX (2 * 16 * NGT * KSEL)

__global__ __launch_bounds__(THREADS) void atss_kernel(
    const float* __restrict__ pred,  // [16][16384][4] cxcywh
    const float* __restrict__ gt,    // [16][128][4]  cxcywh
    float* __restrict__ out)
{
    __shared__ unsigned long long cand[CAP];
    __shared__ unsigned long long topk[KSEL];
    __shared__ int s_cnt;
    __shared__ float ious_s[KSEL];
    __shared__ float r8[8];
    __shared__ float s_mean, s_thr;

    const int task = blockIdx.x;          // b*128 + g
    const int b    = task >> 7;
    const int tid  = threadIdx.x;

    const float* gtp = gt + task * 4;
    const float gcx = gtp[0], gcy = gtp[1], gw = gtp[2], gh = gtp[3];
    const float* pb = pred + (size_t)b * NPRED * 4;
    const float2* pc = reinterpret_cast<const float2*>(pb);  // pc[2*i] = (cx,cy)

    // ---- Phase 1: radius-filtered candidate collection ----
    // Filter metric (fmaf, approximate) only selects a deterministic superset;
    // the exact numpy-f32 sort key (sqrt of non-FMA sum) is computed per hit.
    float Tf = 0.055f;
    int C = 0;
    for (int attempt = 0; attempt < 16; ++attempt) {
        if (tid == 0) s_cnt = 0;
        __syncthreads();
        const float T2 = Tf * Tf;
        #pragma unroll 8
        for (int i = tid; i < NPRED; i += THREADS) {
            const float2 p = pc[i * 2];
            float dx = __fsub_rn(gcx, p.x);
            float dy = __fsub_rn(gcy, p.y);
            float d2f = fmaf(dx, dx, dy * dy);
            if (d2f < T2) {
                // numpy-exact f32 distance: sqrt((dx*dx) + (dy*dy)), no FMA
                float d2 = __fadd_rn(__fmul_rn(dx, dx), __fmul_rn(dy, dy));
                float d  = __fsqrt_rn(d2);
                int pos = atomicAdd(&s_cnt, 1);
                if (pos < CAP)
                    cand[pos] = ((unsigned long long)__float_as_uint(d) << 32)
                              | (unsigned int)i;
            }
        }
        __syncthreads();
        C = s_cnt;
        if (C >= KSEL && C <= CAP) break;
        __syncthreads();                    // protect s_cnt reset vs. reads
        Tf = (C < KSEL) ? Tf * 2.0f : Tf * 0.5f;
    }
    if (C > CAP) C = CAP;  // safety only

    // ---- Phase 2: O(C^2) rank selection (keys unique -> ranks unique) ----
    for (int c = tid; c < C; c += THREADS) {
        const unsigned long long key = cand[c];
        int r = 0;
        for (int j = 0; j < C; ++j)
            r += (cand[j] < key) ? 1 : 0;   // broadcast LDS read, conflict-free
        if (r < KSEL) topk[r] = key;
    }
    __syncthreads();

    // ---- Phase 3: epilogue — IoU, mean+std(ddof=1) threshold, mask (numpy-exact f32) ----
    const float gx1 = __fsub_rn(gcx, __fmul_rn(0.5f, gw));
    const float gy1 = __fsub_rn(gcy, __fmul_rn(0.5f, gh));
    const float gx2 = __fadd_rn(gcx, __fmul_rn(0.5f, gw));
    const float gy2 = __fadd_rn(gcy, __fmul_rn(0.5f, gh));

    float iou = 0.0f, kcx = 0.0f, kcy = 0.0f;
    int idx = 0;
    if (tid < KSEL) {
        unsigned long long key = topk[tid];
        idx = (int)(unsigned int)key;
        const float4 kb = *reinterpret_cast<const float4*>(pb + idx * 4);
        kcx = kb.x; kcy = kb.y;
        float kx1 = __fsub_rn(kb.x, __fmul_rn(0.5f, kb.z));
        float ky1 = __fsub_rn(kb.y, __fmul_rn(0.5f, kb.w));
        float kx2 = __fadd_rn(kb.x, __fmul_rn(0.5f, kb.z));
        float ky2 = __fadd_rn(kb.y, __fmul_rn(0.5f, kb.w));
        float ltx = fmaxf(gx1, kx1), lty = fmaxf(gy1, ky1);
        float rbx = fminf(gx2, kx2), rby = fminf(gy2, ky2);
        float wx = fmaxf(__fsub_rn(rbx, ltx), 0.0f);
        float wy = fmaxf(__fsub_rn(rby, lty), 0.0f);
        float inter = __fmul_rn(wx, wy);
        float ag = __fmul_rn(__fsub_rn(gx2, gx1), __fsub_rn(gy2, gy1));
        float ak = __fmul_rn(__fsub_rn(kx2, kx1), __fsub_rn(ky2, ky1));
        float uni = __fsub_rn(__fadd_rn(ag, ak), inter);
        iou = __fdiv_rn(inter, uni);
        ious_s[tid] = iou;
    }
    __syncthreads();

    // numpy pairwise sum (n=64): r[j] = sequential a[j]+a[j+8]+...+a[j+56],
    // then ((r0+r1)+(r2+r3)) + ((r4+r5)+(r6+r7))
    if (tid < 8) {
        float r = ious_s[tid];
        #pragma unroll
        for (int i = 8; i < 64; i += 8) r = __fadd_rn(r, ious_s[tid + i]);
        r8[tid] = r;
    }
    __syncthreads();
    if (tid == 0) {
        float s = __fadd_rn(
            __fadd_rn(__fadd_rn(r8[0], r8[1]), __fadd_rn(r8[2], r8[3])),
            __fadd_rn(__fadd_rn(r8[4], r8[5]), __fadd_rn(r8[6], r8[7])));
        s_mean = __fdiv_rn(s, 64.0f);
    }
    __syncthreads();
    const float mean = s_mean;
    if (tid < KSEL) {
        float d = __fsub_rn(iou, mean);
        ious_s[tid] = __fmul_rn(d, d);
    }
    __syncthreads();
    if (tid < 8) {
        float r = ious_s[tid];
        #pragma unroll
        for (int i = 8; i < 64; i += 8) r = __fadd_rn(r, ious_s[tid + i]);
        r8[tid] = r;
    }
    __syncthreads();
    if (tid == 0) {
        float s = __fadd_rn(
            __fadd_rn(__fadd_rn(r8[0], r8[1]), __fadd_rn(r8[2], r8[3])),
            __fadd_rn(__fadd_rn(r8[4], r8[5]), __fadd_rn(r8[6], r8[7])));
        float var = __fdiv_rn(s, 63.0f);
        s_thr = __fadd_rn(mean, __fsqrt_rn(var));
    }
    __syncthreads();

    if (tid < KSEL) {
        bool inside = (gx1 <= kcx) && (kcx <= gx2) && (gy1 <= kcy) && (kcy <= gy2);
        bool m = (iou >= s_thr) && inside;
        int o = task * KSEL + tid;
        out[OUT_IOUS + o] = iou;
        out[OUT_MASK + o] = m ? 1.0f : 0.0f;
        out[OUT_KIDX + o] = (float)idx;
    }
}

extern "C" void kernel_launch(void* const* d_in, const int* in_sizes, int n_in,
                              void* d_out, int out_size, void* d_ws, size_t ws_size,
                              hipStream_t stream) {
    const float* pred = (const float*)d_in[0];  // (16,16384,4) f32
    const float* gtb  = (const float*)d_in[1];  // (16,128,4)   f32
    float* out = (float*)d_out;
    dim3 grid(16 * NGT);
    dim3 block(THREADS);
    hipLaunchKernelGGL(atss_kernel, grid, block, 0, stream, pred, gtb, out);
}